// Round 1
// baseline (340.408 us; speedup 1.0000x reference)
//
#include <hip/hip_runtime.h>
#include <hip/hip_bf16.h>
#include <cstdint>

typedef unsigned short ushort_t;
typedef __attribute__((ext_vector_type(8))) short short8;
typedef __attribute__((ext_vector_type(8))) __bf16 bf16x8;
typedef __attribute__((ext_vector_type(4))) float f32x4;
typedef __attribute__((ext_vector_type(4))) ushort_t ushort4v;

// ---------- helpers ----------
__device__ inline ushort_t f2bf(float f) {
    union { float f; unsigned u; } x; x.f = f;
    unsigned r = x.u + 0x7fffu + ((x.u >> 16) & 1u);   // RNE
    return (ushort_t)(r >> 16);
}

__device__ inline bf16x8 ldfrag(const ushort_t* p) {
    short8 s = *(const short8*)p;
    return __builtin_bit_cast(bf16x8, s);
}

__device__ inline f32x4 mfma16(bf16x8 a, bf16x8 b, f32x4 c) {
    return __builtin_amdgcn_mfma_f32_16x16x32_bf16(a, b, c, 0, 0, 0);
}

__device__ inline void glds16(const ushort_t* g, ushort_t* l) {
    __builtin_amdgcn_global_load_lds((const __attribute__((address_space(1))) void*)g,
                                     (__attribute__((address_space(3))) void*)l, 16, 0, 0);
}

// ---------- f32 -> bf16 convert for pre_q / pre_k ----------
__global__ __launch_bounds__(256) void cvt_x(const float* __restrict__ a, const float* __restrict__ b,
                                             ushort_t* __restrict__ oa, ushort_t* __restrict__ ob) {
    int i = (blockIdx.x * 256 + threadIdx.x) * 4;
    float4 va = *(const float4*)(a + i);
    float4 vb = *(const float4*)(b + i);
    ushort4v pa = {f2bf(va.x), f2bf(va.y), f2bf(va.z), f2bf(va.w)};
    ushort4v pb = {f2bf(vb.x), f2bf(vb.y), f2bf(vb.z), f2bf(vb.w)};
    *(ushort4v*)(oa + i) = pa;
    *(ushort4v*)(ob + i) = pb;
}

// ---------- weight transpose + convert: out[n][k] = W[k][n], bf16 ----------
__global__ __launch_bounds__(256) void wtrans(const float* __restrict__ W0, const float* __restrict__ W1,
                                              const float* __restrict__ W2, const float* __restrict__ W3,
                                              ushort_t* __restrict__ out) {
    const int z = blockIdx.z;
    const float* W = (z == 0) ? W0 : (z == 1) ? W1 : (z == 2) ? W2 : W3;
    ushort_t* o = out + (size_t)z * (1u << 20);
    __shared__ float tile[32][33];
    const int tx = threadIdx.x, ty = threadIdx.y;  // (32,8)
    const int bx = blockIdx.x * 32, by = blockIdx.y * 32;
#pragma unroll
    for (int r = 0; r < 4; ++r)
        tile[ty + r * 8][tx] = W[(size_t)(by + ty + r * 8) * 1024 + bx + tx];
    __syncthreads();
#pragma unroll
    for (int r = 0; r < 4; ++r)
        o[(size_t)(bx + ty + r * 8) * 1024 + by + tx] = f2bf(tile[tx][ty + r * 8]);
}

// ---------- 128x128 GEMM, A[4096][1024] bf16 row-major, Wt[n][k] bf16 ----------
// MODE 0: QKV. bid: g = bid>>8 (0=Q w/ A1, 1=K w/ A2, 2=V w/ A2); writes Q/K as
//         [b][h][l][d], V transposed [b][h][d][l], all bf16.
// MODE 1: O-proj. Writes f32 x = acc + bias + resid to oX[m][n].
template <int MODE>
__global__ __launch_bounds__(256) void gemm128(
    const ushort_t* __restrict__ A1, const ushort_t* __restrict__ A2,
    const ushort_t* __restrict__ Wt,
    const float* __restrict__ bias0, const float* __restrict__ bias1, const float* __restrict__ bias2,
    ushort_t* __restrict__ oQ, ushort_t* __restrict__ oK, ushort_t* __restrict__ oVt,
    const float* __restrict__ resid, float* __restrict__ oX) {
    const int t = threadIdx.x;
    const int bid = blockIdx.x;
    int g, mb, nb;
    const float* bias;
    const ushort_t* Wg;
    const ushort_t* Ab;
    if (MODE == 0) {
        g = bid >> 8;
        int rem = bid & 255;
        mb = rem & 31;
        nb = rem >> 5;
        Wg = Wt + (size_t)g * (1u << 20);
        bias = (g == 0) ? bias0 : (g == 1) ? bias1 : bias2;
        Ab = (g == 0) ? A1 : A2;
    } else {
        g = 0;
        mb = bid & 31;
        nb = bid >> 5;
        Wg = Wt;
        bias = bias0;
        Ab = A1;
    }
    const int m0 = mb * 128, n0 = nb * 128;

    __shared__ ushort_t As[128 * 32];
    __shared__ ushort_t Bs[128 * 32];
    const int row4 = t >> 2, c8 = (t & 3) * 8;
    const ushort_t* Ag = Ab + (size_t)(m0 + row4) * 1024 + c8;
    const ushort_t* Bg = Wg + (size_t)(n0 + row4) * 1024 + c8;
    ushort_t* Al = As + row4 * 32 + c8;
    ushort_t* Bl = Bs + row4 * 32 + c8;

    const int lane = t & 63, wid = t >> 6;
    const int wm = wid >> 1, wn = wid & 1;
    const int lr = lane & 15, lk = (lane >> 4) * 8;

    float bn[4];
#pragma unroll
    for (int j = 0; j < 4; ++j) bn[j] = bias[n0 + wn * 64 + j * 16 + lr];
    f32x4 acc[4][4];
#pragma unroll
    for (int i = 0; i < 4; ++i)
#pragma unroll
        for (int j = 0; j < 4; ++j) acc[i][j] = (f32x4){bn[j], bn[j], bn[j], bn[j]};

    for (int kt = 0; kt < 1024; kt += 32) {
        __syncthreads();
        glds16(Ag + kt, Al);
        glds16(Ag + kt + 64 * 1024, Al + 64 * 32);
        glds16(Bg + kt, Bl);
        glds16(Bg + kt + 64 * 1024, Bl + 64 * 32);
        __syncthreads();
        bf16x8 af[4], bfr[4];
#pragma unroll
        for (int i = 0; i < 4; ++i) af[i] = ldfrag(As + (wm * 64 + i * 16 + lr) * 32 + lk);
#pragma unroll
        for (int j = 0; j < 4; ++j) bfr[j] = ldfrag(Bs + (wn * 64 + j * 16 + lr) * 32 + lk);
#pragma unroll
        for (int i = 0; i < 4; ++i)
#pragma unroll
            for (int j = 0; j < 4; ++j) acc[i][j] = mfma16(af[i], bfr[j], acc[i][j]);
    }

#pragma unroll
    for (int i = 0; i < 4; ++i) {
#pragma unroll
        for (int j = 0; j < 4; ++j) {
            f32x4 v = acc[i][j];
            const int n = n0 + wn * 64 + j * 16 + lr;
#pragma unroll
            for (int jj = 0; jj < 4; ++jj) {
                const int m = m0 + wm * 64 + i * 16 + (lane >> 4) * 4 + jj;
                const float val = v[jj];
                if (MODE == 0) {
                    const int b = m >> 11, ll = m & 2047;
                    const int h = n >> 6, d = n & 63;
                    if (g == 0)
                        oQ[(((size_t)(b * 16 + h) * 2048) + ll) * 64 + d] = f2bf(val);
                    else if (g == 1)
                        oK[(((size_t)(b * 16 + h) * 2048) + ll) * 64 + d] = f2bf(val);
                    else
                        oVt[((size_t)(b * 16 + h) * 64 + d) * 2048 + ll] = f2bf(val);
                } else {
                    oX[(size_t)m * 1024 + n] = val + resid[(size_t)m * 1024 + n];
                }
            }
        }
    }
}

// ---------- flash attention: 1 wave per 16 q-rows ----------
__global__ __launch_bounds__(64) void attn_k(const ushort_t* __restrict__ Qg, const ushort_t* __restrict__ Kg,
                                             const ushort_t* __restrict__ Vtg, ushort_t* __restrict__ Cg) {
    const int lane = threadIdx.x;
    const int bid = blockIdx.x;
    const int qb = bid & 127, bh = bid >> 7;
    const int q0 = qb * 16;
    const int lr = lane & 15, lk = (lane >> 4) * 8;

    const ushort_t* Qp = Qg + ((size_t)bh * 2048 + q0 + lr) * 64 + lk;
    bf16x8 qf0 = ldfrag(Qp), qf1 = ldfrag(Qp + 32);

    f32x4 o0 = {}, o1 = {}, o2 = {}, o3 = {};
    float mrun[4], lrun[4];
#pragma unroll
    for (int jj = 0; jj < 4; ++jj) { mrun[jj] = -3.0e38f; lrun[jj] = 0.f; }

    __shared__ ushort_t P[16 * 32];
    const ushort_t* Kbase = Kg + (size_t)bh * 2048 * 64;
    const ushort_t* Vbase = Vtg + (size_t)bh * 64 * 2048;

    for (int kt = 0; kt < 2048; kt += 32) {
        const ushort_t* Kp = Kbase + (size_t)(kt + lr) * 64 + lk;
        bf16x8 k00 = ldfrag(Kp), k01 = ldfrag(Kp + 32);
        bf16x8 k10 = ldfrag(Kp + 1024), k11 = ldfrag(Kp + 1024 + 32);
        f32x4 s0 = {}, s1 = {};
        s0 = mfma16(qf0, k00, s0);
        s0 = mfma16(qf1, k01, s0);
        s1 = mfma16(qf0, k10, s1);
        s1 = mfma16(qf1, k11, s1);

        float p0v[4], p1v[4];
#pragma unroll
        for (int jj = 0; jj < 4; ++jj) {
            float a0 = s0[jj] * 0.125f, a1 = s1[jj] * 0.125f;
            float mx = fmaxf(a0, a1);
#pragma unroll
            for (int m = 1; m < 16; m <<= 1) mx = fmaxf(mx, __shfl_xor(mx, m, 64));
            float mnew = fmaxf(mrun[jj], mx);
            float sc = __expf(mrun[jj] - mnew);
            float p0 = __expf(a0 - mnew), p1 = __expf(a1 - mnew);
            float rsum = p0 + p1;
#pragma unroll
            for (int m = 1; m < 16; m <<= 1) rsum += __shfl_xor(rsum, m, 64);
            lrun[jj] = lrun[jj] * sc + rsum;
            mrun[jj] = mnew;
            o0[jj] *= sc; o1[jj] *= sc; o2[jj] *= sc; o3[jj] *= sc;
            p0v[jj] = p0; p1v[jj] = p1;
        }
        __syncthreads();
#pragma unroll
        for (int jj = 0; jj < 4; ++jj) {
            const int r = (lane >> 4) * 4 + jj;
            P[r * 32 + lr] = f2bf(p0v[jj]);
            P[r * 32 + 16 + lr] = f2bf(p1v[jj]);
        }
        __syncthreads();
        bf16x8 pa = ldfrag(P + lr * 32 + lk);
        const ushort_t* Vp = Vbase + (size_t)lr * 2048 + kt + lk;
        bf16x8 v0 = ldfrag(Vp);
        bf16x8 v1 = ldfrag(Vp + 16 * 2048);
        bf16x8 v2 = ldfrag(Vp + 32 * 2048);
        bf16x8 v3 = ldfrag(Vp + 48 * 2048);
        o0 = mfma16(pa, v0, o0);
        o1 = mfma16(pa, v1, o1);
        o2 = mfma16(pa, v2, o2);
        o3 = mfma16(pa, v3, o3);
    }

    const int b = bh >> 4, h = bh & 15;
#pragma unroll
    for (int jj = 0; jj < 4; ++jj) {
        const float inv = 1.0f / lrun[jj];
        const int l = q0 + (lane >> 4) * 4 + jj;
        ushort_t* cp = Cg + ((size_t)(b * 2048 + l) * 1024) + h * 64;
        cp[lr] = f2bf(o0[jj] * inv);
        cp[16 + lr] = f2bf(o1[jj] * inv);
        cp[32 + lr] = f2bf(o2[jj] * inv);
        cp[48 + lr] = f2bf(o3[jj] * inv);
    }
}

// ---------- LayerNorm, block per row of 1024 ----------
__global__ __launch_bounds__(256) void ln_k(const float* __restrict__ X, const float* __restrict__ gamma,
                                            const float* __restrict__ beta, float* __restrict__ out) {
    const int row = blockIdx.x, t = threadIdx.x;
    const float4 x = ((const float4*)(X + (size_t)row * 1024))[t];
    float s = x.x + x.y + x.z + x.w;
    float s2 = x.x * x.x + x.y * x.y + x.z * x.z + x.w * x.w;
#pragma unroll
    for (int m = 1; m < 64; m <<= 1) {
        s += __shfl_xor(s, m, 64);
        s2 += __shfl_xor(s2, m, 64);
    }
    __shared__ float rs[4], rq[4];
    if ((t & 63) == 0) { rs[t >> 6] = s; rq[t >> 6] = s2; }
    __syncthreads();
    const float S = rs[0] + rs[1] + rs[2] + rs[3];
    const float S2 = rq[0] + rq[1] + rq[2] + rq[3];
    const float mu = S * (1.0f / 1024.0f);
    const float var = S2 * (1.0f / 1024.0f) - mu * mu;
    const float r = rsqrtf(var + 1e-5f);
    const float4 gg = ((const float4*)gamma)[t];
    const float4 bb = ((const float4*)beta)[t];
    float4 o;
    o.x = (x.x - mu) * r * gg.x + bb.x;
    o.y = (x.y - mu) * r * gg.y + bb.y;
    o.z = (x.z - mu) * r * gg.z + bb.z;
    o.w = (x.w - mu) * r * gg.w + bb.w;
    ((float4*)(out + (size_t)row * 1024))[t] = o;
}

// ---------- launch ----------
extern "C" void kernel_launch(void* const* d_in, const int* in_sizes, int n_in,
                              void* d_out, int out_size, void* d_ws, size_t ws_size,
                              hipStream_t stream) {
    (void)in_sizes; (void)n_in; (void)out_size; (void)ws_size;
    const float* pre_q = (const float*)d_in[0];
    const float* pre_k = (const float*)d_in[1];
    const float* Wq = (const float*)d_in[2];
    const float* bq = (const float*)d_in[3];
    const float* Wk = (const float*)d_in[4];
    const float* bk = (const float*)d_in[5];
    const float* Wv = (const float*)d_in[6];
    const float* bv = (const float*)d_in[7];
    const float* Wo = (const float*)d_in[8];
    const float* bo = (const float*)d_in[9];
    const float* gamma = (const float*)d_in[10];
    const float* beta = (const float*)d_in[11];
    float* out = (float*)d_out;
    char* ws = (char*)d_ws;
    const size_t MB = 1024 * 1024;
    ushort_t* Xq = (ushort_t*)(ws);             // 8 MB  bf16 pre_q
    ushort_t* Xk = (ushort_t*)(ws + 8 * MB);    // 8 MB  bf16 pre_k
    ushort_t* Wt = (ushort_t*)(ws + 16 * MB);   // 8 MB  W^T bf16 x4 (q,k,v,o)
    ushort_t* Qb = (ushort_t*)(ws + 24 * MB);   // 8 MB  Q [b,h,l,d]
    ushort_t* Kb = (ushort_t*)(ws + 32 * MB);   // 8 MB  K [b,h,l,d]
    ushort_t* Vt = (ushort_t*)(ws + 40 * MB);   // 8 MB  V [b,h,d,l]
    ushort_t* CTX = (ushort_t*)(ws + 48 * MB);  // 8 MB  ctx [b,l,h*64+d]
    float* Xres = (float*)(ws + 24 * MB);       // 16 MB f32, aliases Qb/Kb (dead by then)

    cvt_x<<<4096, 256, 0, stream>>>(pre_q, pre_k, Xq, Xk);
    wtrans<<<dim3(32, 32, 4), dim3(32, 8), 0, stream>>>(Wq, Wk, Wv, Wo, Wt);
    gemm128<0><<<768, 256, 0, stream>>>(Xq, Xk, Wt, bq, bk, bv, Qb, Kb, Vt, nullptr, nullptr);
    attn_k<<<4096, 64, 0, stream>>>(Qb, Kb, Vt, CTX);
    gemm128<1><<<256, 256, 0, stream>>>(CTX, nullptr, Wt + 3 * (1u << 20), bo, nullptr, nullptr,
                                        nullptr, nullptr, nullptr, pre_q, Xres);
    ln_k<<<4096, 256, 0, stream>>>(Xres, gamma, beta, out);
}

// Round 2
// 336.296 us; speedup vs baseline: 1.0122x; 1.0122x over previous
//
#include <hip/hip_runtime.h>
#include <hip/hip_bf16.h>
#include <cstdint>

typedef unsigned short ushort_t;
typedef __attribute__((ext_vector_type(8))) short short8;
typedef __attribute__((ext_vector_type(8))) __bf16 bf16x8;
typedef __attribute__((ext_vector_type(4))) float f32x4;
typedef __attribute__((ext_vector_type(4))) ushort_t ushort4v;

// ---------- helpers ----------
__device__ inline ushort_t f2bf(float f) {
    union { float f; unsigned u; } x; x.f = f;
    unsigned r = x.u + 0x7fffu + ((x.u >> 16) & 1u);   // RNE
    return (ushort_t)(r >> 16);
}

__device__ inline bf16x8 ldfrag(const ushort_t* p) {
    short8 s = *(const short8*)p;
    return __builtin_bit_cast(bf16x8, s);
}

__device__ inline f32x4 mfma16(bf16x8 a, bf16x8 b, f32x4 c) {
    return __builtin_amdgcn_mfma_f32_16x16x32_bf16(a, b, c, 0, 0, 0);
}

__device__ inline void glds16(const ushort_t* g, ushort_t* l) {
    __builtin_amdgcn_global_load_lds((const __attribute__((address_space(1))) void*)g,
                                     (__attribute__((address_space(3))) void*)l, 16, 0, 0);
}

// ---------- f32 -> bf16 convert for pre_q / pre_k ----------
__global__ __launch_bounds__(256) void cvt_x(const float* __restrict__ a, const float* __restrict__ b,
                                             ushort_t* __restrict__ oa, ushort_t* __restrict__ ob) {
    int i = (blockIdx.x * 256 + threadIdx.x) * 4;
    float4 va = *(const float4*)(a + i);
    float4 vb = *(const float4*)(b + i);
    ushort4v pa = {f2bf(va.x), f2bf(va.y), f2bf(va.z), f2bf(va.w)};
    ushort4v pb = {f2bf(vb.x), f2bf(vb.y), f2bf(vb.z), f2bf(vb.w)};
    *(ushort4v*)(oa + i) = pa;
    *(ushort4v*)(ob + i) = pb;
}

// ---------- weight transpose + convert: out[n][k] = W[k][n], bf16 ----------
__global__ __launch_bounds__(256) void wtrans(const float* __restrict__ W0, const float* __restrict__ W1,
                                              const float* __restrict__ W2, const float* __restrict__ W3,
                                              ushort_t* __restrict__ out) {
    const int z = blockIdx.z;
    const float* W = (z == 0) ? W0 : (z == 1) ? W1 : (z == 2) ? W2 : W3;
    ushort_t* o = out + (size_t)z * (1u << 20);
    __shared__ float tile[32][33];
    const int tx = threadIdx.x, ty = threadIdx.y;  // (32,8)
    const int bx = blockIdx.x * 32, by = blockIdx.y * 32;
#pragma unroll
    for (int r = 0; r < 4; ++r)
        tile[ty + r * 8][tx] = W[(size_t)(by + ty + r * 8) * 1024 + bx + tx];
    __syncthreads();
#pragma unroll
    for (int r = 0; r < 4; ++r)
        o[(size_t)(bx + ty + r * 8) * 1024 + by + tx] = f2bf(tile[tx][ty + r * 8]);
}

// ---------- 128x128 GEMM, A[4096][1024] bf16 row-major, Wt[n][k] bf16 ----------
template <int MODE>
__global__ __launch_bounds__(256) void gemm128(
    const ushort_t* __restrict__ A1, const ushort_t* __restrict__ A2,
    const ushort_t* __restrict__ Wt,
    const float* __restrict__ bias0, const float* __restrict__ bias1, const float* __restrict__ bias2,
    ushort_t* __restrict__ oQ, ushort_t* __restrict__ oK, ushort_t* __restrict__ oVt,
    const float* __restrict__ resid, float* __restrict__ oX) {
    const int t = threadIdx.x;
    const int bid = blockIdx.x;
    int g, mb, nb;
    const float* bias;
    const ushort_t* Wg;
    const ushort_t* Ab;
    if (MODE == 0) {
        g = bid >> 8;
        int rem = bid & 255;
        mb = rem & 31;
        nb = rem >> 5;
        Wg = Wt + (size_t)g * (1u << 20);
        bias = (g == 0) ? bias0 : (g == 1) ? bias1 : bias2;
        Ab = (g == 0) ? A1 : A2;
    } else {
        g = 0;
        mb = bid & 31;
        nb = bid >> 5;
        Wg = Wt;
        bias = bias0;
        Ab = A1;
    }
    const int m0 = mb * 128, n0 = nb * 128;

    __shared__ ushort_t As[128 * 32];
    __shared__ ushort_t Bs[128 * 32];
    const int row4 = t >> 2, c8 = (t & 3) * 8;
    const ushort_t* Ag = Ab + (size_t)(m0 + row4) * 1024 + c8;
    const ushort_t* Bg = Wg + (size_t)(n0 + row4) * 1024 + c8;
    ushort_t* Al = As + row4 * 32 + c8;
    ushort_t* Bl = Bs + row4 * 32 + c8;

    const int lane = t & 63, wid = t >> 6;
    const int wm = wid >> 1, wn = wid & 1;
    const int lr = lane & 15, lk = (lane >> 4) * 8;

    float bn[4];
#pragma unroll
    for (int j = 0; j < 4; ++j) bn[j] = bias[n0 + wn * 64 + j * 16 + lr];
    f32x4 acc[4][4];
#pragma unroll
    for (int i = 0; i < 4; ++i)
#pragma unroll
        for (int j = 0; j < 4; ++j) acc[i][j] = (f32x4){bn[j], bn[j], bn[j], bn[j]};

    for (int kt = 0; kt < 1024; kt += 32) {
        __syncthreads();
        glds16(Ag + kt, Al);
        glds16(Ag + kt + 64 * 1024, Al + 64 * 32);
        glds16(Bg + kt, Bl);
        glds16(Bg + kt + 64 * 1024, Bl + 64 * 32);
        __syncthreads();
        bf16x8 af[4], bfr[4];
#pragma unroll
        for (int i = 0; i < 4; ++i) af[i] = ldfrag(As + (wm * 64 + i * 16 + lr) * 32 + lk);
#pragma unroll
        for (int j = 0; j < 4; ++j) bfr[j] = ldfrag(Bs + (wn * 64 + j * 16 + lr) * 32 + lk);
#pragma unroll
        for (int i = 0; i < 4; ++i)
#pragma unroll
            for (int j = 0; j < 4; ++j) acc[i][j] = mfma16(af[i], bfr[j], acc[i][j]);
    }

#pragma unroll
    for (int i = 0; i < 4; ++i) {
#pragma unroll
        for (int j = 0; j < 4; ++j) {
            f32x4 v = acc[i][j];
            const int n = n0 + wn * 64 + j * 16 + lr;
#pragma unroll
            for (int jj = 0; jj < 4; ++jj) {
                const int m = m0 + wm * 64 + i * 16 + (lane >> 4) * 4 + jj;
                const float val = v[jj];
                if (MODE == 0) {
                    const int b = m >> 11, ll = m & 2047;
                    const int h = n >> 6, d = n & 63;
                    if (g == 0)
                        oQ[(((size_t)(b * 16 + h) * 2048) + ll) * 64 + d] = f2bf(val);
                    else if (g == 1)
                        oK[(((size_t)(b * 16 + h) * 2048) + ll) * 64 + d] = f2bf(val);
                    else
                        oVt[((size_t)(b * 16 + h) * 64 + d) * 2048 + ll] = f2bf(val);
                } else {
                    oX[(size_t)m * 1024 + n] = val + resid[(size_t)m * 1024 + n];
                }
            }
        }
    }
}

// ---------- flash attention v2: swapped QK^T, in-lane softmax ----------
// 1 wave / 16 q-rows, KVBLK=64, defer-max, no barriers, XCD-swizzled grid.
// S^T = mfma(K-frag(A), Q-frag(B)) -> lane holds S^T[kpos][q=lane&15], 16 kpos.
// ctx^T = mfma(V^T-frag(A), P^T-frag(B)) -> lane holds ctx^T[d][q=lane&15].
__global__ __launch_bounds__(64) void attn_k(const ushort_t* __restrict__ Qg, const ushort_t* __restrict__ Kg,
                                             const ushort_t* __restrict__ Vtg, ushort_t* __restrict__ Cg) {
    const int lane = threadIdx.x;
    const int bid = blockIdx.x;
    // XCD swizzle: xcd = bid&7 (dispatch heuristic); 4 heads per XCD.
    const int xcd = bid & 7, jx = bid >> 3;
    const int bh = (xcd << 2) | (jx >> 7);
    const int qb = jx & 127;
    const int q0 = qb * 16;
    const int lr = lane & 15;      // q (QK/PV B-col), kpos-row (K A), d-row (V A)
    const int g = lane >> 4;       // 0..3
    const int lk = g * 8;
    const int c = lr & 3;          // LDS xor key
    const int h2 = g >> 1, G = g & 1;

    // Q as B-frag: B[k=d][col=q=lr]
    const ushort_t* Qp = Qg + ((size_t)bh * 2048 + q0 + lr) * 64 + lk;
    bf16x8 qf0 = ldfrag(Qp), qf1 = ldfrag(Qp + 32);

    f32x4 o[4] = {};               // ctx^T: o[df], rows d=16df+4g+jj, col q=lr
    float mrun = -3.0e38f, lrun = 0.f;

    __shared__ ushort_t P[16][72]; // [q][kpos], pad+xor swizzled
    const ushort_t* Kbase = Kg + (size_t)bh * 2048 * 64;
    const ushort_t* Vbase = Vtg + (size_t)bh * 64 * 2048;

    for (int kt = 0; kt < 2048; kt += 64) {
        // ---- S^T = K-block x Q ----
        f32x4 st[4];
#pragma unroll
        for (int f = 0; f < 4; ++f) {
            const ushort_t* Kp = Kbase + (size_t)(kt + 16 * f + lr) * 64 + lk;
            f32x4 s = {};
            s = mfma16(ldfrag(Kp), qf0, s);
            s = mfma16(ldfrag(Kp + 32), qf1, s);
            st[f] = s;
        }
        // ---- in-lane softmax for q=lr over 64 kpos (16 in-lane + cross-g) ----
        float sv[16];
#pragma unroll
        for (int f = 0; f < 4; ++f)
#pragma unroll
            for (int jj = 0; jj < 4; ++jj) sv[f * 4 + jj] = st[f][jj] * 0.125f;
        float mx = sv[0];
#pragma unroll
        for (int i = 1; i < 16; ++i) mx = fmaxf(mx, sv[i]);
        mx = fmaxf(mx, __shfl_xor(mx, 16, 64));
        mx = fmaxf(mx, __shfl_xor(mx, 32, 64));
        if (__any(mx > mrun + 8.0f)) {          // defer-max (THR=8)
            const float mnew = fmaxf(mrun, mx);
            const float sc = __expf(mrun - mnew);
            lrun *= sc;
#pragma unroll
            for (int df = 0; df < 4; ++df)
#pragma unroll
                for (int z = 0; z < 4; ++z) o[df][z] *= sc;
            mrun = mnew;
        }
        float p[16];
        float rs = 0.f;
#pragma unroll
        for (int i = 0; i < 16; ++i) { p[i] = __expf(sv[i] - mrun); rs += p[i]; }
        rs += __shfl_xor(rs, 16, 64);
        rs += __shfl_xor(rs, 32, 64);
        lrun += rs;
        // ---- pack P^T rows (kpos = 16f+4g+jj) into LDS row q=lr ----
#pragma unroll
        for (int f = 0; f < 4; ++f) {
            ushort4v pk = {f2bf(p[f * 4 + 0]), f2bf(p[f * 4 + 1]), f2bf(p[f * 4 + 2]), f2bf(p[f * 4 + 3])};
            *(ushort4v*)&P[lr][16 * (f ^ c) + 4 * g] = pk;
        }
        asm volatile("s_waitcnt lgkmcnt(0)" ::: "memory");
        // ---- ctx^T += V^T-block x P^T ----
#pragma unroll
        for (int b = 0; b < 2; ++b) {
            bf16x8 pf = ldfrag(&P[lr][16 * ((2 * b + h2) ^ c) + 8 * G]);
#pragma unroll
            for (int df = 0; df < 4; ++df) {
                const ushort_t* Vp = Vbase + (size_t)(16 * df + lr) * 2048 + kt + 32 * b + lk;
                o[df] = mfma16(ldfrag(Vp), pf, o[df]);
            }
        }
    }

    const int b = bh >> 4, hh = bh & 15;
    const float inv = 1.0f / lrun;
    const int l = q0 + lr;
    ushort_t* cp = Cg + ((size_t)(b * 2048 + l) * 1024) + hh * 64;
#pragma unroll
    for (int df = 0; df < 4; ++df) {
        ushort4v cw = {f2bf(o[df][0] * inv), f2bf(o[df][1] * inv), f2bf(o[df][2] * inv), f2bf(o[df][3] * inv)};
        *(ushort4v*)(cp + 16 * df + 4 * g) = cw;
    }
}

// ---------- LayerNorm, block per row of 1024 ----------
__global__ __launch_bounds__(256) void ln_k(const float* __restrict__ X, const float* __restrict__ gamma,
                                            const float* __restrict__ beta, float* __restrict__ out) {
    const int row = blockIdx.x, t = threadIdx.x;
    const float4 x = ((const float4*)(X + (size_t)row * 1024))[t];
    float s = x.x + x.y + x.z + x.w;
    float s2 = x.x * x.x + x.y * x.y + x.z * x.z + x.w * x.w;
#pragma unroll
    for (int m = 1; m < 64; m <<= 1) {
        s += __shfl_xor(s, m, 64);
        s2 += __shfl_xor(s2, m, 64);
    }
    __shared__ float rs[4], rq[4];
    if ((t & 63) == 0) { rs[t >> 6] = s; rq[t >> 6] = s2; }
    __syncthreads();
    const float S = rs[0] + rs[1] + rs[2] + rs[3];
    const float S2 = rq[0] + rq[1] + rq[2] + rq[3];
    const float mu = S * (1.0f / 1024.0f);
    const float var = S2 * (1.0f / 1024.0f) - mu * mu;
    const float r = rsqrtf(var + 1e-5f);
    const float4 gg = ((const float4*)gamma)[t];
    const float4 bb = ((const float4*)beta)[t];
    float4 o;
    o.x = (x.x - mu) * r * gg.x + bb.x;
    o.y = (x.y - mu) * r * gg.y + bb.y;
    o.z = (x.z - mu) * r * gg.z + bb.z;
    o.w = (x.w - mu) * r * gg.w + bb.w;
    ((float4*)(out + (size_t)row * 1024))[t] = o;
}

// ---------- launch ----------
extern "C" void kernel_launch(void* const* d_in, const int* in_sizes, int n_in,
                              void* d_out, int out_size, void* d_ws, size_t ws_size,
                              hipStream_t stream) {
    (void)in_sizes; (void)n_in; (void)out_size; (void)ws_size;
    const float* pre_q = (const float*)d_in[0];
    const float* pre_k = (const float*)d_in[1];
    const float* Wq = (const float*)d_in[2];
    const float* bq = (const float*)d_in[3];
    const float* Wk = (const float*)d_in[4];
    const float* bk = (const float*)d_in[5];
    const float* Wv = (const float*)d_in[6];
    const float* bv = (const float*)d_in[7];
    const float* Wo = (const float*)d_in[8];
    const float* bo = (const float*)d_in[9];
    const float* gamma = (const float*)d_in[10];
    const float* beta = (const float*)d_in[11];
    float* out = (float*)d_out;
    char* ws = (char*)d_ws;
    const size_t MB = 1024 * 1024;
    ushort_t* Xq = (ushort_t*)(ws);             // 8 MB  bf16 pre_q
    ushort_t* Xk = (ushort_t*)(ws + 8 * MB);    // 8 MB  bf16 pre_k
    ushort_t* Wt = (ushort_t*)(ws + 16 * MB);   // 8 MB  W^T bf16 x4 (q,k,v,o)
    ushort_t* Qb = (ushort_t*)(ws + 24 * MB);   // 8 MB  Q [b,h,l,d]
    ushort_t* Kb = (ushort_t*)(ws + 32 * MB);   // 8 MB  K [b,h,l,d]
    ushort_t* Vt = (ushort_t*)(ws + 40 * MB);   // 8 MB  V [b,h,d,l]
    ushort_t* CTX = (ushort_t*)(ws + 48 * MB);  // 8 MB  ctx [b,l,h*64+d]
    float* Xres = (float*)(ws + 24 * MB);       // 16 MB f32, aliases Qb/Kb (dead by then)

    cvt_x<<<4096, 256, 0, stream>>>(pre_q, pre_k, Xq, Xk);
    wtrans<<<dim3(32, 32, 4), dim3(32, 8), 0, stream>>>(Wq, Wk, Wv, Wo, Wt);
    gemm128<0><<<768, 256, 0, stream>>>(Xq, Xk, Wt, bq, bk, bv, Qb, Kb, Vt, nullptr, nullptr);
    attn_k<<<4096, 64, 0, stream>>>(Qb, Kb, Vt, CTX);
    gemm128<1><<<256, 256, 0, stream>>>(CTX, nullptr, Wt + 3 * (1u << 20), bo, nullptr, nullptr,
                                        nullptr, nullptr, nullptr, pre_q, Xres);
    ln_k<<<4096, 256, 0, stream>>>(Xres, gamma, beta, out);
}

// Round 4
// 187.430 us; speedup vs baseline: 1.8162x; 1.7942x over previous
//
#include <hip/hip_runtime.h>
#include <hip/hip_bf16.h>
#include <cstdint>

typedef unsigned short ushort_t;
typedef __attribute__((ext_vector_type(8))) short short8;
typedef __attribute__((ext_vector_type(8))) __bf16 bf16x8;
typedef __attribute__((ext_vector_type(4))) float f32x4;
typedef __attribute__((ext_vector_type(4))) ushort_t ushort4v;
typedef __attribute__((ext_vector_type(2))) unsigned int uint2v;

// ---------- helpers ----------
__device__ inline ushort_t f2bf(float f) {
    union { float f; unsigned u; } x; x.f = f;
    unsigned r = x.u + 0x7fffu + ((x.u >> 16) & 1u);   // RNE
    return (ushort_t)(r >> 16);
}

__device__ inline unsigned pkbf(float a, float b) {
    __hip_bfloat162 h = __float22bfloat162_rn(float2{a, b});   // v_cvt_pk_bf16_f32
    unsigned r;
    __builtin_memcpy(&r, &h, 4);
    return r;
}

__device__ inline bf16x8 ldfrag(const ushort_t* p) {
    short8 s = *(const short8*)p;
    return __builtin_bit_cast(bf16x8, s);
}

__device__ inline f32x4 mfma16(bf16x8 a, bf16x8 b, f32x4 c) {
    return __builtin_amdgcn_mfma_f32_16x16x32_bf16(a, b, c, 0, 0, 0);
}

__device__ inline void glds16(const ushort_t* g, ushort_t* l) {
    __builtin_amdgcn_global_load_lds((const __attribute__((address_space(1))) void*)g,
                                     (__attribute__((address_space(3))) void*)l, 16, 0, 0);
}

// ---------- f32 -> bf16 convert for pre_q / pre_k ----------
__global__ __launch_bounds__(256) void cvt_x(const float* __restrict__ a, const float* __restrict__ b,
                                             ushort_t* __restrict__ oa, ushort_t* __restrict__ ob) {
    int i = (blockIdx.x * 256 + threadIdx.x) * 4;
    float4 va = *(const float4*)(a + i);
    float4 vb = *(const float4*)(b + i);
    ushort4v pa = {f2bf(va.x), f2bf(va.y), f2bf(va.z), f2bf(va.w)};
    ushort4v pb = {f2bf(vb.x), f2bf(vb.y), f2bf(vb.z), f2bf(vb.w)};
    *(ushort4v*)(oa + i) = pa;
    *(ushort4v*)(ob + i) = pb;
}

// ---------- weight transpose + convert: out[n][k] = W[k][n], bf16 ----------
__global__ __launch_bounds__(256) void wtrans(const float* __restrict__ W0, const float* __restrict__ W1,
                                              const float* __restrict__ W2, const float* __restrict__ W3,
                                              ushort_t* __restrict__ out) {
    const int z = blockIdx.z;
    const float* W = (z == 0) ? W0 : (z == 1) ? W1 : (z == 2) ? W2 : W3;
    ushort_t* o = out + (size_t)z * (1u << 20);
    __shared__ float tile[32][33];
    const int tx = threadIdx.x, ty = threadIdx.y;  // (32,8)
    const int bx = blockIdx.x * 32, by = blockIdx.y * 32;
#pragma unroll
    for (int r = 0; r < 4; ++r)
        tile[ty + r * 8][tx] = W[(size_t)(by + ty + r * 8) * 1024 + bx + tx];
    __syncthreads();
#pragma unroll
    for (int r = 0; r < 4; ++r)
        o[(size_t)(bx + ty + r * 8) * 1024 + by + tx] = f2bf(tile[tx][ty + r * 8]);
}

// ---------- 128x128 GEMM, A[4096][1024] bf16 row-major, Wt[n][k] bf16 ----------
template <int MODE>
__global__ __launch_bounds__(256) void gemm128(
    const ushort_t* __restrict__ A1, const ushort_t* __restrict__ A2,
    const ushort_t* __restrict__ Wt,
    const float* __restrict__ bias0, const float* __restrict__ bias1, const float* __restrict__ bias2,
    ushort_t* __restrict__ oQ, ushort_t* __restrict__ oK, ushort_t* __restrict__ oVt,
    const float* __restrict__ resid, float* __restrict__ oX) {
    const int t = threadIdx.x;
    const int bid = blockIdx.x;
    int g, mb, nb;
    const float* bias;
    const ushort_t* Wg;
    const ushort_t* Ab;
    if (MODE == 0) {
        g = bid >> 8;
        int rem = bid & 255;
        mb = rem & 31;
        nb = rem >> 5;
        Wg = Wt + (size_t)g * (1u << 20);
        bias = (g == 0) ? bias0 : (g == 1) ? bias1 : bias2;
        Ab = (g == 0) ? A1 : A2;
    } else {
        g = 0;
        mb = bid & 31;
        nb = bid >> 5;
        Wg = Wt;
        bias = bias0;
        Ab = A1;
    }
    const int m0 = mb * 128, n0 = nb * 128;

    __shared__ ushort_t As[128 * 32];
    __shared__ ushort_t Bs[128 * 32];
    const int row4 = t >> 2, c8 = (t & 3) * 8;
    const ushort_t* Ag = Ab + (size_t)(m0 + row4) * 1024 + c8;
    const ushort_t* Bg = Wg + (size_t)(n0 + row4) * 1024 + c8;
    ushort_t* Al = As + row4 * 32 + c8;
    ushort_t* Bl = Bs + row4 * 32 + c8;

    const int lane = t & 63, wid = t >> 6;
    const int wm = wid >> 1, wn = wid & 1;
    const int lr = lane & 15, lk = (lane >> 4) * 8;

    float bn[4];
#pragma unroll
    for (int j = 0; j < 4; ++j) bn[j] = bias[n0 + wn * 64 + j * 16 + lr];
    f32x4 acc[4][4];
#pragma unroll
    for (int i = 0; i < 4; ++i)
#pragma unroll
        for (int j = 0; j < 4; ++j) acc[i][j] = (f32x4){bn[j], bn[j], bn[j], bn[j]};

    for (int kt = 0; kt < 1024; kt += 32) {
        __syncthreads();
        glds16(Ag + kt, Al);
        glds16(Ag + kt + 64 * 1024, Al + 64 * 32);
        glds16(Bg + kt, Bl);
        glds16(Bg + kt + 64 * 1024, Bl + 64 * 32);
        __syncthreads();
        bf16x8 af[4], bfr[4];
#pragma unroll
        for (int i = 0; i < 4; ++i) af[i] = ldfrag(As + (wm * 64 + i * 16 + lr) * 32 + lk);
#pragma unroll
        for (int j = 0; j < 4; ++j) bfr[j] = ldfrag(Bs + (wn * 64 + j * 16 + lr) * 32 + lk);
#pragma unroll
        for (int i = 0; i < 4; ++i)
#pragma unroll
            for (int j = 0; j < 4; ++j) acc[i][j] = mfma16(af[i], bfr[j], acc[i][j]);
    }

#pragma unroll
    for (int i = 0; i < 4; ++i) {
#pragma unroll
        for (int j = 0; j < 4; ++j) {
            f32x4 v = acc[i][j];
            const int n = n0 + wn * 64 + j * 16 + lr;
#pragma unroll
            for (int jj = 0; jj < 4; ++jj) {
                const int m = m0 + wm * 64 + i * 16 + (lane >> 4) * 4 + jj;
                const float val = v[jj];
                if (MODE == 0) {
                    const int b = m >> 11, ll = m & 2047;
                    const int h = n >> 6, d = n & 63;
                    if (g == 0)
                        oQ[(((size_t)(b * 16 + h) * 2048) + ll) * 64 + d] = f2bf(val);
                    else if (g == 1)
                        oK[(((size_t)(b * 16 + h) * 2048) + ll) * 64 + d] = f2bf(val);
                    else
                        oVt[((size_t)(b * 16 + h) * 64 + d) * 2048 + ll] = f2bf(val);
                } else {
                    oX[(size_t)m * 1024 + n] = val + resid[(size_t)m * 1024 + n];
                }
            }
        }
    }
}

// ---------- flash attention v3: cooperative 4-wave, LDS-staged K/V, 2-phase dbuf ----------
// Block = 256 thr (4 waves) owns 64 q-rows of one (b,h); wave w owns rows w*16..+15.
// K tile [64 kpos][64 d], V^T tile [64 d][64 kpos] staged via global_load_lds with
// chunk-XOR swizzle (pre-swizzled global source, linear LDS dest, swizzled read).
// Swapped QK^T (S^T = K x Q) keeps softmax in-lane; P^T per-wave in LDS feeds PV.
__global__ __launch_bounds__(256, 4) void attn_k(const ushort_t* __restrict__ Qg, const ushort_t* __restrict__ Kg,
                                                 const ushort_t* __restrict__ Vtg, ushort_t* __restrict__ Cg) {
    __shared__ ushort_t Ks[2][64 * 64];
    __shared__ ushort_t Vs[2][64 * 64];
    __shared__ ushort_t Ps[4][16 * 64];

    const int t = threadIdx.x;
    const int lane = t & 63, w = t >> 6;
    const int bid = blockIdx.x;
    const int xcd = bid & 7, j = bid >> 3;     // 8 XCDs x 128 blocks
    const int bh = (xcd << 2) | (j >> 5);      // 4 heads per XCD -> 2MB K/V in its L2
    const int qb = j & 31;
    const int q0 = qb * 64 + w * 16;
    const int lr = lane & 15, g = lane >> 4;
    const int lk = g * 8;
    const int c = lr & 3;                      // P xor key
    const int hx = lr & 7;                     // K/V chunk-xor key (row&7)
    const int h2 = g >> 1, G = g & 1;

    const ushort_t* Kbase = Kg + (size_t)bh * (2048 * 64);
    const ushort_t* Vbase = Vtg + (size_t)bh * (64 * 2048);

    // staging geometry: 8 regions of 512 elems; wave w covers regions {w, w+4}
    const int srow = lane >> 3;                         // row-in-region
    const int sc8 = (((lane & 7) ^ srow) * 8);          // xor-swizzled source chunk

    // Q as B-frag (col=q=lr, k=d)
    const ushort_t* Qp = Qg + ((size_t)bh * 2048 + q0 + lr) * 64 + lk;
    const bf16x8 qf0 = ldfrag(Qp), qf1 = ldfrag(Qp + 32);

    f32x4 o[4] = {};                // ctx^T: rows d=16df+4g+jj, col q=lr
    float mrun = -3.0e38f, lrun = 0.f;
    const float CS = 0.125f * 1.44269504089f;   // fold 1/sqrt(64) into exp2

#define STAGE(buf, kt)                                                                   \
    {                                                                                    \
        _Pragma("unroll") for (int r = 0; r < 2; ++r) {                                  \
            const int m = w + 4 * r;                                                     \
            const int row = m * 8 + srow;                                                \
            glds16(Kbase + (size_t)((kt) + row) * 64 + sc8, &Ks[buf][m * 512 + lane * 8]); \
            glds16(Vbase + (size_t)row * 2048 + (kt) + sc8, &Vs[buf][m * 512 + lane * 8]); \
        }                                                                                \
    }

    STAGE(0, 0);
    asm volatile("s_waitcnt vmcnt(0)" ::: "memory");
    __syncthreads();

    int cur = 0;
    for (int kt = 0; kt < 2048; kt += 64) {
        if (kt < 2048 - 64) STAGE(cur ^ 1, kt + 64);

        // ---- S^T = K-block x Q (K from LDS, swizzled chunks) ----
        const int cc0 = (g ^ hx) * 8, cc1 = ((g + 4) ^ hx) * 8;
        f32x4 st[4];
#pragma unroll
        for (int f = 0; f < 4; ++f) {
            const int rb = (16 * f + lr) * 64;
            f32x4 s = {};
            s = mfma16(ldfrag(&Ks[cur][rb + cc0]), qf0, s);
            s = mfma16(ldfrag(&Ks[cur][rb + cc1]), qf1, s);
            st[f] = s;
        }

        // ---- in-lane online softmax for q=lr over 64 kpos (raw units) ----
        float sv[16];
#pragma unroll
        for (int f = 0; f < 4; ++f)
#pragma unroll
            for (int jj = 0; jj < 4; ++jj) sv[f * 4 + jj] = st[f][jj];
        float mx = sv[0];
#pragma unroll
        for (int i = 1; i < 16; ++i) mx = fmaxf(mx, sv[i]);
        mx = fmaxf(mx, __shfl_xor(mx, 16, 64));
        mx = fmaxf(mx, __shfl_xor(mx, 32, 64));
        if (__any(mx > mrun + 64.0f)) {            // defer-max, THR=8 in scaled units
            const float mnew = fmaxf(mrun, mx);
            const float sc = __builtin_exp2f((mrun - mnew) * CS);
            lrun *= sc;
#pragma unroll
            for (int df = 0; df < 4; ++df)
#pragma unroll
                for (int z = 0; z < 4; ++z) o[df][z] *= sc;
            mrun = mnew;
        }
        float rs = 0.f;
#pragma unroll
        for (int f = 0; f < 4; ++f) {
            const float p0 = __builtin_exp2f((sv[f * 4 + 0] - mrun) * CS);
            const float p1 = __builtin_exp2f((sv[f * 4 + 1] - mrun) * CS);
            const float p2 = __builtin_exp2f((sv[f * 4 + 2] - mrun) * CS);
            const float p3 = __builtin_exp2f((sv[f * 4 + 3] - mrun) * CS);
            rs += (p0 + p1) + (p2 + p3);
            uint2v pw = {pkbf(p0, p1), pkbf(p2, p3)};
            *(uint2v*)&Ps[w][lr * 64 + 16 * (f ^ c) + 4 * g] = pw;
        }
        rs += __shfl_xor(rs, 16, 64);
        rs += __shfl_xor(rs, 32, 64);
        lrun += rs;

        asm volatile("s_waitcnt lgkmcnt(0)" ::: "memory");

        // ---- ctx^T += V^T-block x P^T (V from LDS, swizzled chunks) ----
#pragma unroll
        for (int b = 0; b < 2; ++b) {
            bf16x8 pf = ldfrag(&Ps[w][lr * 64 + 16 * ((2 * b + h2) ^ c) + 8 * G]);
            const int vc = ((4 * b + g) ^ hx) * 8;
#pragma unroll
            for (int df = 0; df < 4; ++df) {
                o[df] = mfma16(ldfrag(&Vs[cur][(16 * df + lr) * 64 + vc]), pf, o[df]);
            }
        }

        asm volatile("s_waitcnt vmcnt(0)" ::: "memory");
        __syncthreads();
        cur ^= 1;
    }
#undef STAGE

    const int b = bh >> 4, hh = bh & 15;
    const float inv = 1.0f / lrun;
    const int l = q0 + lr;
    ushort_t* cp = Cg + ((size_t)(b * 2048 + l) * 1024) + hh * 64;
#pragma unroll
    for (int df = 0; df < 4; ++df) {
        uint2v cw = {pkbf(o[df][0] * inv, o[df][1] * inv), pkbf(o[df][2] * inv, o[df][3] * inv)};
        *(uint2v*)(cp + 16 * df + 4 * g) = cw;
    }
}

// ---------- LayerNorm, block per row of 1024 ----------
__global__ __launch_bounds__(256) void ln_k(const float* __restrict__ X, const float* __restrict__ gamma,
                                            const float* __restrict__ beta, float* __restrict__ out) {
    const int row = blockIdx.x, t = threadIdx.x;
    const float4 x = ((const float4*)(X + (size_t)row * 1024))[t];
    float s = x.x + x.y + x.z + x.w;
    float s2 = x.x * x.x + x.y * x.y + x.z * x.z + x.w * x.w;
#pragma unroll
    for (int m = 1; m < 64; m <<= 1) {
        s += __shfl_xor(s, m, 64);
        s2 += __shfl_xor(s2, m, 64);
    }
    __shared__ float rs[4], rq[4];
    if ((t & 63) == 0) { rs[t >> 6] = s; rq[t >> 6] = s2; }
    __syncthreads();
    const float S = rs[0] + rs[1] + rs[2] + rs[3];
    const float S2 = rq[0] + rq[1] + rq[2] + rq[3];
    const float mu = S * (1.0f / 1024.0f);
    const float var = S2 * (1.0f / 1024.0f) - mu * mu;
    const float r = rsqrtf(var + 1e-5f);
    const float4 gg = ((const float4*)gamma)[t];
    const float4 bb = ((const float4*)beta)[t];
    float4 o;
    o.x = (x.x - mu) * r * gg.x + bb.x;
    o.y = (x.y - mu) * r * gg.y + bb.y;
    o.z = (x.z - mu) * r * gg.z + bb.z;
    o.w = (x.w - mu) * r * gg.w + bb.w;
    ((float4*)(out + (size_t)row * 1024))[t] = o;
}

// ---------- launch ----------
extern "C" void kernel_launch(void* const* d_in, const int* in_sizes, int n_in,
                              void* d_out, int out_size, void* d_ws, size_t ws_size,
                              hipStream_t stream) {
    (void)in_sizes; (void)n_in; (void)out_size; (void)ws_size;
    const float* pre_q = (const float*)d_in[0];
    const float* pre_k = (const float*)d_in[1];
    const float* Wq = (const float*)d_in[2];
    const float* bq = (const float*)d_in[3];
    const float* Wk = (const float*)d_in[4];
    const float* bk = (const float*)d_in[5];
    const float* Wv = (const float*)d_in[6];
    const float* bv = (const float*)d_in[7];
    const float* Wo = (const float*)d_in[8];
    const float* bo = (const float*)d_in[9];
    const float* gamma = (const float*)d_in[10];
    const float* beta = (const float*)d_in[11];
    float* out = (float*)d_out;
    char* ws = (char*)d_ws;
    const size_t MB = 1024 * 1024;
    ushort_t* Xq = (ushort_t*)(ws);             // 8 MB  bf16 pre_q
    ushort_t* Xk = (ushort_t*)(ws + 8 * MB);    // 8 MB  bf16 pre_k
    ushort_t* Wt = (ushort_t*)(ws + 16 * MB);   // 8 MB  W^T bf16 x4 (q,k,v,o)
    ushort_t* Qb = (ushort_t*)(ws + 24 * MB);   // 8 MB  Q [b,h,l,d]
    ushort_t* Kb = (ushort_t*)(ws + 32 * MB);   // 8 MB  K [b,h,l,d]
    ushort_t* Vt = (ushort_t*)(ws + 40 * MB);   // 8 MB  V [b,h,d,l]
    ushort_t* CTX = (ushort_t*)(ws + 48 * MB);  // 8 MB  ctx [b,l,h*64+d]
    float* Xres = (float*)(ws + 24 * MB);       // 16 MB f32, aliases Qb/Kb (dead by then)

    cvt_x<<<4096, 256, 0, stream>>>(pre_q, pre_k, Xq, Xk);
    wtrans<<<dim3(32, 32, 4), dim3(32, 8), 0, stream>>>(Wq, Wk, Wv, Wo, Wt);
    gemm128<0><<<768, 256, 0, stream>>>(Xq, Xk, Wt, bq, bk, bv, Qb, Kb, Vt, nullptr, nullptr);
    attn_k<<<1024, 256, 0, stream>>>(Qb, Kb, Vt, CTX);
    gemm128<1><<<256, 256, 0, stream>>>(CTX, nullptr, Wt + 3 * (1u << 20), bo, nullptr, nullptr,
                                        nullptr, nullptr, nullptr, pre_q, Xres);
    ln_k<<<4096, 256, 0, stream>>>(Xres, gamma, beta, out);
}